// Round 1
// 692.958 us; speedup vs baseline: 1.2411x; 1.2411x over previous
//
#include <hip/hip_runtime.h>

// Upsample 2x via upfirdn2d([1,3,3,1], factor 2).
//   x:   (8, 64, 256, 256) fp32
//   out: (8, 64, 511, 511) fp32
//
// Quad formulation: output rows (2q-1, 2q) and cols (2c-1, 2c) depend only on
// input rows (q-1, q) and cols (c-1, c).  Per-dim tap weights (inv = 2/sum(k)):
//   odd  output index: (top/left = k2*inv, bottom/right = k0*inv)
//   even output index: (top/left = k3*inv, bottom/right = k1*inv)
// Row/col -1 is zero padding (only quads q==0 / c==0 touch it).
//
// One thread per quad-column (256 threads = full row of quads).  Each block
// walks a strip of QY=32 quad-rows for one (b,c) image, carrying the previous
// input row in registers so every input element is fetched from HBM once.
// Grid: 512 images x 8 strips = 4096 blocks (vs 523k before) -> per-thread
// loop amortizes dispatch overhead and gives memory-level parallelism.

#define IN_H 256
#define IN_W 256
#define OUT_H 511
#define OUT_W 511
#define N_BC (8 * 64)
#define QY 32                   // quad-rows per strip
#define STRIPS (IN_H / QY)      // 8 strips per image

__global__ __launch_bounds__(256) void Upsample_64948495450678_kernel(
    const float* __restrict__ x,
    const float* __restrict__ k1d,
    float* __restrict__ out)
{
    const int qx  = threadIdx.x;            // quad col 0..255
    const int blk = blockIdx.x;
    const int bc  = blk >> 3;               // blk / STRIPS
    const int y0  = (blk & (STRIPS - 1)) * QY;

    // Uniform per-thread tap weights from the actual kernel input.
    const float k0 = k1d[0], k1 = k1d[1], k2 = k1d[2], k3 = k1d[3];
    const float inv = 2.0f / (k0 + k1 + k2 + k3);
    const float k0i = k0 * inv, k1i = k1 * inv, k2i = k2 * inv, k3i = k3 * inv;

    const float* __restrict__ xp = x + (size_t)bc * (IN_H * IN_W);
    const float* pin = xp + (size_t)y0 * IN_W + qx;
    float* pout = out + (size_t)bc * ((size_t)OUT_H * OUT_W)
                      + (size_t)(2 * y0) * OUT_W + 2 * qx;

    // Carried top row (quad row y0 reads input rows y0-1, y0).
    float a, am;
    if (y0 == 0) {
        a = 0.0f; am = 0.0f;                // input row -1 is zero padding
    } else {
        a  = pin[-IN_W];
        am = qx ? pin[-IN_W - 1] : 0.0f;    // input col -1 is zero padding
    }

    #pragma unroll 4
    for (int i = 0; i < QY; ++i) {
        const float b  = pin[0];
        const float bm = qx ? pin[-1] : 0.0f;

        // Horizontal passes (top/bottom input row x odd/even output col).
        const float Hto = k2i * am + k0i * a;
        const float Hte = k3i * am + k1i * a;
        const float Hbo = k2i * bm + k0i * b;
        const float Hbe = k3i * bm + k1i * b;

        // Odd output row 2*qy-1 (doesn't exist for quad row 0).
        if (y0 + i > 0) {
            if (qx > 0) pout[-OUT_W - 1] = k2i * Hto + k0i * Hbo;
            pout[-OUT_W] = k2i * Hte + k0i * Hbe;
        }
        // Even output row 2*qy.
        if (qx > 0) pout[-1] = k3i * Hto + k1i * Hbo;
        pout[0] = k3i * Hte + k1i * Hbe;

        a = b; am = bm;
        pin  += IN_W;
        pout += 2 * OUT_W;
    }
}

extern "C" void kernel_launch(void* const* d_in, const int* in_sizes, int n_in,
                              void* d_out, int out_size, void* d_ws, size_t ws_size,
                              hipStream_t stream) {
    const float* x   = (const float*)d_in[0];
    const float* k1d = (const float*)d_in[1];
    float* out = (float*)d_out;

    dim3 block(256, 1, 1);
    dim3 grid(N_BC * STRIPS, 1, 1);   // 4096 blocks
    Upsample_64948495450678_kernel<<<grid, block, 0, stream>>>(x, k1d, out);
}

// Round 2
// 671.558 us; speedup vs baseline: 1.2806x; 1.0319x over previous
//
#include <hip/hip_runtime.h>

// Upsample 2x via upfirdn2d([1,3,3,1], factor 2).
//   x:   (8, 64, 256, 256) fp32
//   out: (8, 64, 511, 511) fp32
//
// Separable form. For output col o: q = (o>>1) + (o&1), inputs x[q-1], x[q],
// weights (o odd) ? (k2,k0)*inv : (k3,k1)*inv, inv = 2/sum(k).  Same vertically.
// H(r,o) = horizontal filter of input row r at output col o.  Then
//   out[2r-1][o] = k2i*H(r-1,o) + k0i*H(r,o)     (odd rows; skipped at r==0)
//   out[2r  ][o] = k3i*H(r-1,o) + k1i*H(r,o)
//
// Dense-lane mapping: each 128-thread group handles one half-strip of HR=16
// input rows; lane tx owns output cols {tx, tx+128, tx+256, tx+384} so every
// store instruction is 64 consecutive dwords (fully dense — OUT_W=511 is odd,
// so vector stores would be misaligned; dense scalar is the coalescing-clean
// pattern).  H is carried vertically in registers: each input row is fetched
// from HBM once (plus one halo row per half-strip).

#define IN_H 256
#define IN_W 256
#define OUT_H 511
#define OUT_W 511
#define N_BC (8 * 64)
#define QY 32                  // input rows per block
#define STRIPS (IN_H / QY)     // 8 blocks per image
#define HR (QY / 2)            // 16 rows per 128-thread half-strip group

__global__ __launch_bounds__(256) void Upsample_64948495450678_kernel(
    const float* __restrict__ x,
    const float* __restrict__ k1d,
    float* __restrict__ out)
{
    const int t  = threadIdx.x;
    const int tx = t & 127;                 // lane within group
    const int ty = t >> 7;                  // which half-strip
    const int bc = blockIdx.x >> 3;         // / STRIPS
    const int r0 = (blockIdx.x & (STRIPS - 1)) * QY + ty * HR;

    // Uniform tap weights from the actual kernel input.
    const float k0 = k1d[0], k1 = k1d[1], k2 = k1d[2], k3 = k1d[3];
    const float inv = 2.0f / (k0 + k1 + k2 + k3);
    const float k0i = k0*inv, k1i = k1*inv, k2i = k2*inv, k3i = k3*inv;

    // Col parity is the same for all 4 slots (stride 128 is even).
    const int   p  = tx & 1;
    const float wA = p ? k2i : k3i;         // weight on input col q-1
    const float wB = p ? k0i : k1i;         // weight on input col q
    const int   q0 = (tx >> 1) + p;         // input col q for slot 0 (o = tx)
    const bool  s3 = (tx < 127);            // slot 3 col == 511 doesn't exist for tx==127

    const float* __restrict__ xim = x + (size_t)bc * (IN_H * IN_W);
    const float* pin = xim + (size_t)r0 * IN_W;

    // Horizontal filter of one input row at this lane's 4 output cols.
    auto hrow = [&](const float* __restrict__ prow, float H[4]) {
        const float xa0 = (q0 > 0) ? prow[q0 - 1] : 0.0f;   // col -1 zero pad (tx==0 only)
        H[0] = wA * xa0            + wB * prow[q0];
        H[1] = wA * prow[q0 + 63]  + wB * prow[q0 + 64];
        H[2] = wA * prow[q0 + 127] + wB * prow[q0 + 128];
        if (s3)
            H[3] = wA * prow[q0 + 191] + wB * prow[q0 + 192];
        else
            H[3] = 0.0f;
    };

    // Carried previous-row H (input row r0-1; zero pad for the image top).
    float Hp[4];
    if (r0 == 0) {
        Hp[0] = Hp[1] = Hp[2] = Hp[3] = 0.0f;
    } else {
        hrow(pin - IN_W, Hp);
    }

    float* pout = out + (size_t)bc * ((size_t)OUT_H * OUT_W)
                      + (size_t)(2 * r0) * OUT_W + tx;

    #pragma unroll 4
    for (int i = 0; i < HR; ++i) {
        float H[4];
        hrow(pin, H);

        if (r0 + i > 0) {                   // odd output row 2r-1
            float* po = pout - OUT_W;
            po[0]   = k2i * Hp[0] + k0i * H[0];
            po[128] = k2i * Hp[1] + k0i * H[1];
            po[256] = k2i * Hp[2] + k0i * H[2];
            if (s3) po[384] = k2i * Hp[3] + k0i * H[3];
        }
        // even output row 2r
        pout[0]   = k3i * Hp[0] + k1i * H[0];
        pout[128] = k3i * Hp[1] + k1i * H[1];
        pout[256] = k3i * Hp[2] + k1i * H[2];
        if (s3) pout[384] = k3i * Hp[3] + k1i * H[3];

        Hp[0] = H[0]; Hp[1] = H[1]; Hp[2] = H[2]; Hp[3] = H[3];
        pin  += IN_W;
        pout += 2 * OUT_W;
    }
}

extern "C" void kernel_launch(void* const* d_in, const int* in_sizes, int n_in,
                              void* d_out, int out_size, void* d_ws, size_t ws_size,
                              hipStream_t stream) {
    const float* x   = (const float*)d_in[0];
    const float* k1d = (const float*)d_in[1];
    float* out = (float*)d_out;

    dim3 block(256, 1, 1);
    dim3 grid(N_BC * STRIPS, 1, 1);   // 4096 blocks
    Upsample_64948495450678_kernel<<<grid, block, 0, stream>>>(x, k1d, out);
}

// Round 3
// 637.845 us; speedup vs baseline: 1.3483x; 1.0529x over previous
//
#include <hip/hip_runtime.h>

// Upsample 2x via upfirdn2d([1,3,3,1], factor 2).
//   x:   (8, 64, 256, 256) fp32
//   out: (8, 64, 511, 511) fp32
//
// Separable form, same math as the verified round-2 kernel:
//   q = (o>>1)+(o&1); H(r,o) = wA*x[r][q-1] + wB*x[r][q],
//   wA/wB = (o odd) ? (k2,k0)*inv : (k3,k1)*inv, inv = 2/sum(k)
//   out[2r-1][o] = k2i*H(r-1,o) + k0i*H(r,o)   (odd rows; absent at r==0)
//   out[2r  ][o] = k3i*H(r-1,o) + k1i*H(r,o)
//
// NEW: LDS-staged flat flush. OUT_W=511 (odd) makes per-row vector stores
// impossible, but consecutive output rows are contiguous, so each block's
// 8-output-row chunk (16352 B) is staged in LDS and flushed as a flat
// float4 stream (scalar head/tail of <=3 dwords fixes the 4B-granular image
// base). Stores become dense aligned dwordx4 — the fill-kernel pattern that
// hits ~6.2 TB/s on this machine — instead of scalar dwords.
// Input is still read once per element via the per-thread vertical H carry.

#define IN_H 256
#define IN_W 256
#define OUT_H 511
#define OUT_W 511
#define N_BC (8 * 64)
#define STRIP 32                 // input rows per block
#define STRIPS (IN_H / STRIP)    // 8 blocks per image
#define CH 4                     // input rows per chunk -> 8 output rows
#define CHUNKS (STRIP / CH)
#define LDS_DW (8 * OUT_W + 8)   // 8 out rows + pad dwords

__global__ __launch_bounds__(256) void Upsample_64948495450678_kernel(
    const float* __restrict__ x,
    const float* __restrict__ k1d,
    float* __restrict__ out)
{
    __shared__ __align__(16) float lds[LDS_DW];

    const int t  = threadIdx.x;
    const int bc = blockIdx.x >> 3;                  // / STRIPS
    const int r0 = (blockIdx.x & (STRIPS - 1)) * STRIP;

    // Uniform tap weights from the actual kernel input.
    const float k0 = k1d[0], k1 = k1d[1], k2 = k1d[2], k3 = k1d[3];
    const float inv = 2.0f / (k0 + k1 + k2 + k3);
    const float k0i = k0*inv, k1i = k1*inv, k2i = k2*inv, k3i = k3*inv;

    // Lane t owns output cols {t, t+256} (t+256 only if t<255). Parity equal.
    const int   p  = t & 1;
    const float wA = p ? k2i : k3i;                  // weight on input col q-1
    const float wB = p ? k0i : k1i;                  // weight on input col q
    const int   q0 = (t >> 1) + p;                   // input col for out col t
    const int   q1 = q0 + 128;                       // input col for out col t+256
    const bool  s1 = (t < 255);

    const float* __restrict__ xim = x + (size_t)bc * (IN_H * IN_W);

    // Carried H of previous input row (r0-1); zero pad at image top.
    float Hp0, Hp1;
    if (r0 == 0) {
        Hp0 = Hp1 = 0.0f;
    } else {
        const float* pr = xim + (size_t)(r0 - 1) * IN_W;
        const float a0 = (q0 > 0) ? pr[q0 - 1] : 0.0f;
        Hp0 = wA * a0 + wB * pr[q0];
        Hp1 = s1 ? (wA * pr[q1 - 1] + wB * pr[q1]) : 0.0f;
    }

    const size_t img_b = (size_t)bc * ((size_t)OUT_H * OUT_W * 4);  // bytes
    char* __restrict__ outb = (char*)out;

    for (int c = 0; c < CHUNKS; ++c) {
        const int rc        = r0 + c * CH;
        const int row_start = (rc == 0) ? 0 : (2 * rc - 1);
        const int nrows     = (rc == 0) ? 7 : 8;
        const size_t S      = img_b + (size_t)row_start * (OUT_W * 4);
        const int pd        = (int)(S & 15) >> 2;    // LDS pad dwords

        // ---- compute 8 (7) output rows into LDS ----
        for (int j = 0; j < CH; ++j) {
            const int r = rc + j;
            const float* pr = xim + (size_t)r * IN_W;
            const float a0 = (q0 > 0) ? pr[q0 - 1] : 0.0f;
            const float H0 = wA * a0 + wB * pr[q0];
            const float H1 = s1 ? (wA * pr[q1 - 1] + wB * pr[q1]) : 0.0f;

            if (r > 0) {                             // odd output row 2r-1
                float* L = lds + pd + (size_t)((2*r - 1) - row_start) * OUT_W;
                L[t] = k2i * Hp0 + k0i * H0;
                if (s1) L[t + 256] = k2i * Hp1 + k0i * H1;
            }
            {                                        // even output row 2r
                float* L = lds + pd + (size_t)(2*r - row_start) * OUT_W;
                L[t] = k3i * Hp0 + k1i * H0;
                if (s1) L[t + 256] = k3i * Hp1 + k1i * H1;
            }
            Hp0 = H0; Hp1 = H1;
        }
        __syncthreads();

        // ---- flat float4 flush: bytes [S, S + nrows*2044) ----
        {
            const int nb     = nrows * (OUT_W * 4);
            const int headB  = (16 - (int)(S & 15)) & 15;
            const int nvec   = (nb - headB) >> 4;
            const int tailB  = (nb - headB) & 15;
            const int basedw = pd + (headB >> 2);    // 16B-aligned LDS dword base
            char* gp = outb + S;

            if (t < (headB >> 2))
                *(float*)(gp + 4 * t) = lds[pd + t];

            for (int i = t; i < nvec; i += 256) {
                const float4 v = *(const float4*)(lds + basedw + 4 * i);
                *(float4*)(gp + headB + 16 * i) = v;
            }

            if (t < (tailB >> 2))
                *(float*)(gp + headB + 16 * nvec + 4 * t) =
                    lds[basedw + 4 * nvec + t];
        }
        __syncthreads();
    }
}

extern "C" void kernel_launch(void* const* d_in, const int* in_sizes, int n_in,
                              void* d_out, int out_size, void* d_ws, size_t ws_size,
                              hipStream_t stream) {
    const float* x   = (const float*)d_in[0];
    const float* k1d = (const float*)d_in[1];
    float* out = (float*)d_out;

    dim3 block(256, 1, 1);
    dim3 grid(N_BC * STRIPS, 1, 1);   // 4096 blocks
    Upsample_64948495450678_kernel<<<grid, block, 0, stream>>>(x, k1d, out);
}